// Round 9
// baseline (3418.456 us; speedup 1.0000x reference)
//
#include <hip/hip_runtime.h>

typedef unsigned short u16;
typedef unsigned int   u32;
typedef _Float16 f16x8 __attribute__((ext_vector_type(8)));
typedef _Float16 f16x4 __attribute__((ext_vector_type(4)));
typedef float  f32x4  __attribute__((ext_vector_type(4)));
typedef int    i32x4  __attribute__((ext_vector_type(4)));
typedef u32    u32x2  __attribute__((ext_vector_type(2)));

#define Bn 8
#define Sn 96
#define Tn 96
#define Hn 64
#define H2n 128
#define NDIAG 191
#define NROUND 192
#define STR 72            // state row stride (u16): 144B, 16B-aligned
#define ARR (Sn*STR)      // 6912 u16 per state array; 4 arrays = 55,296 B static LDS
#define LO_SCALE 2048.0f  // keeps W_lo fp16-normal (avoids MFMA subnormal flush)
#define LO_INV   4.8828125e-4f

__device__ __forceinline__ u32 pack2f16(float a, float b){
  _Float16 ha = (_Float16)a, hb = (_Float16)b;       // v_cvt_f16_f32 (RNE)
  return (u32)__builtin_bit_cast(u16, ha) | ((u32)__builtin_bit_cast(u16, hb) << 16);
}
__device__ __forceinline__ float fast_tanh(float x){
  float y = fminf(fmaxf(x+x, -30.f), 30.f);
  float e = __expf(y);
  return (e-1.f)*__builtin_amdgcn_rcpf(e+1.f);
}

// Prologue: depth-0 input projections + depth-0 bias into ws (fp32).
__global__ __launch_bounds__(64) void proj0_kernel(
  const float* __restrict__ src, const float* __restrict__ trg,
  const float* __restrict__ Wix, const float* __restrict__ Wiy,
  const float* __restrict__ bx, const float* __restrict__ by,
  float* __restrict__ ws)
{
  const int row = blockIdx.x, g = blockIdx.y, b = blockIdx.z;
  const int n = threadIdx.x;
  const float* x = (g == 0) ? (src + (b*Sn + row)*Hn) : (trg + (b*Tn + row)*Hn);
  const float* W = (g == 0) ? Wix : Wiy;   // depth-0 slice
  float a = (g == 0) ? bx[n] : by[n];
  #pragma unroll 8
  for (int f = 0; f < Hn; ++f) a = fmaf(x[f], W[f*Hn + n], a);
  ws[((size_t)(b*2 + g)*Sn + row)*Hn + n] = a;
}

// Fused lag-1 wavefront (round-7 structure), one block per sample, 16 waves =
// (g, nt, dep). State = single fp16 LDS array per (dep,stream); weights are
// fp16 hi + fp16 scaled-lo, two MFMA chains merged by one exact fma -> weights
// effectively fp32-exact; only h's fp16 rounding (random per step) remains.
// Round = { C: ds_read state + 2-chain MFMA + tanh (regs) ; bar ; W: state+out ; bar }.
__global__ __launch_bounds__(1024, 4) void grid_rnn_fused(
  const float* __restrict__ Whx, const float* __restrict__ Why,
  const float* __restrict__ Wix, const float* __restrict__ Wiy,
  const float* __restrict__ bx,  const float* __restrict__ by,
  const int* __restrict__ src_lens, const int* __restrict__ trg_lens,
  float* __restrict__ out, const float* __restrict__ ws)
{
  __shared__ __align__(16) u16 sX0[ARR];  // hx depth-0, indexed by col j
  __shared__ __align__(16) u16 sY0[ARR];  // hy depth-0, indexed by row i
  __shared__ __align__(16) u16 sX1[ARR];  // hx depth-1
  __shared__ __align__(16) u16 sY1[ARR];  // hy depth-1

  const int b    = blockIdx.x;
  const int tid  = threadIdx.x;
  const int lane = tid & 63;
  const int wid  = tid >> 6;
  const int q    = lane >> 4;
  const int c    = lane & 15;
  const int dep  = wid & 1;
  const int nt   = (wid >> 1) & 3;
  const int g    = wid >> 3;
  const int sl = src_lens[b], tl = trg_lens[b];

  u16* const mX = dep ? sX1 : sX0;
  u16* const mY = dep ? sY1 : sY0;
  u16* const pS = (g == 0) ? sX0 : sY0;   // dep1 projection operand source

  for (int idx = tid; idx < ARR/2; idx += 1024){
    ((u32*)sX0)[idx]=0u; ((u32*)sY0)[idx]=0u;
    ((u32*)sX1)[idx]=0u; ((u32*)sY1)[idx]=0u;
  }

  // ---- weights (own depth, 16-feature tile): fp16 hi + fp16 scaled-lo
  const float* Wh = (g ? Why : Whx) + dep*H2n*Hn;
  const int nb = nt*16 + c;
  i32x4 whf_h[4], whf_l[4];
  #pragma unroll
  for (int kk = 0; kk < 4; ++kk){
    #pragma unroll
    for (int p = 0; p < 4; ++p){
      float w0 = Wh[(kk*32 + q*8 + 2*p    )*Hn + nb];
      float w1 = Wh[(kk*32 + q*8 + 2*p + 1)*Hn + nb];
      float h0 = (float)(_Float16)w0, h1 = (float)(_Float16)w1;
      whf_h[kk][p] = (int)pack2f16(w0, w1);
      whf_l[kk][p] = (int)pack2f16((w0 - h0)*LO_SCALE, (w1 - h1)*LO_SCALE);
    }
  }
  const float* Wi = (g ? Wiy : Wix) + Hn*Hn;   // depth-1 slice (dep1 only)
  i32x4 wif_h[2], wif_l[2];
  #pragma unroll
  for (int kk = 0; kk < 2; ++kk){
    #pragma unroll
    for (int p = 0; p < 4; ++p){
      float w0 = Wi[(kk*32 + q*8 + 2*p    )*Hn + nb];
      float w1 = Wi[(kk*32 + q*8 + 2*p + 1)*Hn + nb];
      float h0 = (float)(_Float16)w0, h1 = (float)(_Float16)w1;
      wif_h[kk][p] = (int)pack2f16(w0, w1);
      wif_l[kk][p] = (int)pack2f16((w0 - h0)*LO_SCALE, (w1 - h1)*LO_SCALE);
    }
  }
  f32x4 bias4;  // depth-1 bias (dep0 gets bias via ws projections)
  {
    const float* bb = (g ? by : bx) + dep*Hn;
    #pragma unroll
    for (int r4 = 0; r4 < 4; ++r4) bias4[r4] = bb[nt*16 + q*4 + r4];
  }
  const float* pxbase = ws + (size_t)(b*2 + g)*Sn*Hn;

  __syncthreads();

  for (int r = 0; r < NROUND; ++r){
    const int myd  = r - dep;
    const bool wact = (myd >= 0) && (myd < NDIAG);
    const int i0 = (myd > Tn-1) ? myd - (Tn-1) : 0;
    const int i1 = (myd < Sn-1) ? myd : Sn-1;
    const int nc = i1 - i0 + 1;
    const int mtiles = (nc + 15) >> 4;

    f32x4 hva[6];       // fp32 h (for out stores)
    u32x2 hpk[6];       // packed fp16 h (for state writes)

    // ---- C phase: read state + compute; no state writes
    #pragma unroll
    for (int u = 0; u < 6; ++u){
      const bool act = wact && (u < mtiles);
      if (!act) continue;
      const int cell = u*16 + c;
      const int cc = (cell < nc) ? cell : nc - 1;
      const int i = i0 + cc, j = myd - i;

      f32x4 acc;
      if (dep == 0){
        acc = *(const f32x4*)(pxbase + (size_t)((g == 0) ? i : j)*Hn + nt*16 + q*4);
      } else {
        acc = bias4;
      }
      f32x4 acc2 = {0.f, 0.f, 0.f, 0.f};
      // recurrence K=128: kk0-1 hx (col j), kk2-3 hy (row i); 2-chain exact weights
      #pragma unroll
      for (int kk = 0; kk < 4; ++kk){
        const int off = (kk < 2) ? (j*STR + kk*32 + q*8) : (i*STR + (kk-2)*32 + q*8);
        const u16* sb = (kk < 2) ? mX : mY;
        i32x4 sv = *(const i32x4*)(sb + off);
        acc  = __builtin_amdgcn_mfma_f32_16x16x32_f16(
                 __builtin_bit_cast(f16x8, whf_h[kk]),
                 __builtin_bit_cast(f16x8, sv), acc,  0, 0, 0);
        acc2 = __builtin_amdgcn_mfma_f32_16x16x32_f16(
                 __builtin_bit_cast(f16x8, whf_l[kk]),
                 __builtin_bit_cast(f16x8, sv), acc2, 0, 0, 0);
      }
      // dep1 projection: operand = dep0's fp16 state slot at (i,j), read directly
      if (dep == 1){
        const int pr = ((g == 0) ? j : i)*STR;
        #pragma unroll
        for (int kk = 0; kk < 2; ++kk){
          i32x4 pv = *(const i32x4*)(pS + pr + kk*32 + q*8);
          acc  = __builtin_amdgcn_mfma_f32_16x16x32_f16(
                   __builtin_bit_cast(f16x8, wif_h[kk]),
                   __builtin_bit_cast(f16x8, pv), acc,  0, 0, 0);
          acc2 = __builtin_amdgcn_mfma_f32_16x16x32_f16(
                   __builtin_bit_cast(f16x8, wif_l[kk]),
                   __builtin_bit_cast(f16x8, pv), acc2, 0, 0, 0);
        }
      }
      #pragma unroll
      for (int r4 = 0; r4 < 4; ++r4) acc[r4] = fmaf(acc2[r4], LO_INV, acc[r4]);

      f32x4 hv;
      #pragma unroll
      for (int r4 = 0; r4 < 4; ++r4) hv[r4] = fast_tanh(acc[r4]);
      hva[u] = hv;
      hpk[u][0] = pack2f16(hv[0], hv[1]);
      hpk[u][1] = pack2f16(hv[2], hv[3]);
    }
    __syncthreads();

    // ---- W phase: state writes (fp16) + masked out writes (fp32)
    #pragma unroll
    for (int u = 0; u < 6; ++u){
      const bool act = wact && (u < mtiles);
      const int cell = u*16 + c;
      if (!act || cell >= nc) continue;
      const int i = i0 + cell, j = myd - i;
      const int n0 = nt*16 + q*4;
      u16* st = ((g == 0) ? (mX + j*STR) : (mY + i*STR)) + n0;
      *(u32x2*)st = hpk[u];
      f32x4 ov = hva[u];
      if (i >= sl || j >= tl) ov = (f32x4)(0.f);
      float* outg = out + ((size_t)((g*2 + dep)*Bn + b)*(Sn*Tn) + i*Tn + j)*Hn + n0;
      *(f32x4*)outg = ov;
    }
    __syncthreads();
  }
}

extern "C" void kernel_launch(void* const* d_in, const int* in_sizes, int n_in,
                              void* d_out, int out_size, void* d_ws, size_t ws_size,
                              hipStream_t stream) {
  (void)in_sizes; (void)n_in; (void)out_size; (void)ws_size;
  proj0_kernel<<<dim3(Sn, 2, Bn), 64, 0, stream>>>(
      (const float*)d_in[0], (const float*)d_in[1],
      (const float*)d_in[2], (const float*)d_in[5],
      (const float*)d_in[4], (const float*)d_in[7],
      (float*)d_ws);
  grid_rnn_fused<<<dim3(Bn), dim3(1024), 0, stream>>>(
      (const float*)d_in[3], (const float*)d_in[6],
      (const float*)d_in[2], (const float*)d_in[5],
      (const float*)d_in[4], (const float*)d_in[7],
      (const int*)d_in[8], (const int*)d_in[9],
      (float*)d_out, (const float*)d_ws);
}

// Round 10
// 1019.105 us; speedup vs baseline: 3.3544x; 3.3544x over previous
//
#include <hip/hip_runtime.h>

typedef unsigned short u16;
typedef unsigned int   u32;
typedef __bf16 bf16x8 __attribute__((ext_vector_type(8)));
typedef float  f32x4  __attribute__((ext_vector_type(4)));
typedef int    i32x4  __attribute__((ext_vector_type(4)));
typedef u32    u32x2  __attribute__((ext_vector_type(2)));

#define Bn 8
#define Sn 96
#define Tn 96
#define Hn 64
#define H2n 128
#define NDIAG 191
#define NROUND 192
#define STR 72            // state row stride (u16): 144B, 16B-aligned, 2-way-max bank aliasing
#define ARR (Sn*STR)      // 6912 u16 per state array; 8 arrays = 110,592 B dynamic LDS

__device__ __forceinline__ float bf2f(u16 u){ return __uint_as_float(((u32)u)<<16); }
__device__ __forceinline__ u16 f2bf_rne(float f){
  u32 u = __float_as_uint(f);
  u += 0x7FFFu + ((u>>16)&1u);
  return (u16)(u>>16);
}
// HW packed fp32->bf16 (RNE): dst = { bf16(b)<<16 | bf16(a) }
__device__ __forceinline__ u32 cvt_pk_bf16(float a, float b){
  u32 r;
  asm("v_cvt_pk_bf16_f32 %0, %1, %2" : "=v"(r) : "v"(a), "v"(b));
  return r;
}
__device__ __forceinline__ float lo16f(u32 u){ return __uint_as_float(u << 16); }
__device__ __forceinline__ float hi16f(u32 u){ return __uint_as_float(u & 0xFFFF0000u); }
__device__ __forceinline__ float fast_tanh(float x){
  float y = fminf(fmaxf(x+x, -30.f), 30.f);
  float e = __expf(y);
  return (e-1.f)*__builtin_amdgcn_rcpf(e+1.f);
}
// Workgroup barrier WITHOUT the vmcnt(0) drain __syncthreads() emits.
// Only LDS ordering (lgkmcnt) is needed across the round-loop barriers:
// in-loop global accesses are write-only stores to per-round-disjoint
// addresses (out) and read-only px loads whose uses carry their own waitcnts.
__device__ __forceinline__ void barrier_lds_only(){
  asm volatile("s_waitcnt vmcnt(63) expcnt(7) lgkmcnt(0)\n\ts_barrier" ::: "memory");
}

// Prologue: depth-0 input projections + bias, px[b,g,row,n] (fp32) into ws.
__global__ __launch_bounds__(64) void proj0_kernel(
  const float* __restrict__ src, const float* __restrict__ trg,
  const float* __restrict__ Wix, const float* __restrict__ Wiy,
  const float* __restrict__ bx, const float* __restrict__ by,
  float* __restrict__ ws)
{
  const int row = blockIdx.x, g = blockIdx.y, b = blockIdx.z;
  const int n = threadIdx.x;
  const float* x = (g == 0) ? (src + (b*Sn + row)*Hn) : (trg + (b*Tn + row)*Hn);
  const float* W = (g == 0) ? Wix : Wiy;   // depth-0 slice
  float a = (g == 0) ? bx[n] : by[n];      // depth-0 bias folded in
  #pragma unroll 8
  for (int f = 0; f < Hn; ++f) a = fmaf(x[f], W[f*Hn + n], a);
  ws[((size_t)(b*2 + g)*Sn + row)*Hn + n] = a;
}

// Fused lag-1 wavefront, 1024 threads = 16 waves: wave = (g, nt, dep).
//   g  = stream (0: hx writes col state sX; 1: hy writes row state sY)
//   nt = 16-feature n-tile [nt*16, nt*16+16)
//   dep= depth; round r: dep0 does diag r, dep1 does diag r-1.
// Depth-1's projection operand hx0/hy0(i,j) comes straight from depth-0's LDS
// state slot (written last round, overwritten only in this round's W phase).
// Round = { C: read state + MFMA + tanh (regs) ; bar ; W: write state + out ; bar }.
__global__ __launch_bounds__(1024, 4) void grid_rnn_fused(
  const float* __restrict__ Whx, const float* __restrict__ Why,
  const float* __restrict__ Wix, const float* __restrict__ Wiy,
  const float* __restrict__ bx,  const float* __restrict__ by,
  const int* __restrict__ src_lens, const int* __restrict__ trg_lens,
  float* __restrict__ out, const float* __restrict__ ws)
{
  extern __shared__ u16 smem[];
  // layout: [X0hi][X0lo][Y0hi][Y0lo][X1hi][X1lo][Y1hi][Y1lo]
  u16* const sXhi0 = smem;           u16* const sXlo0 = smem + ARR;
  u16* const sYhi0 = smem + 2*ARR;   u16* const sYlo0 = smem + 3*ARR;
  u16* const sXhi1 = smem + 4*ARR;   u16* const sXlo1 = smem + 5*ARR;
  u16* const sYhi1 = smem + 6*ARR;   u16* const sYlo1 = smem + 7*ARR;

  const int b    = blockIdx.x;
  const int tid  = threadIdx.x;
  const int lane = tid & 63;
  const int wid  = tid >> 6;
  const int q    = lane >> 4;
  const int c    = lane & 15;
  const int dep  = wid & 1;
  const int nt   = (wid >> 1) & 3;
  const int g    = wid >> 3;
  const int sl = src_lens[b], tl = trg_lens[b];

  u16* const mXhi = dep ? sXhi1 : sXhi0;  u16* const mXlo = dep ? sXlo1 : sXlo0;
  u16* const mYhi = dep ? sYhi1 : sYhi0;  u16* const mYlo = dep ? sYlo1 : sYlo0;
  u16* const pHi = (g == 0) ? sXhi0 : sYhi0;   // depth-0 state for dep1 projection
  u16* const pLo = (g == 0) ? sXlo0 : sYlo0;

  for (int idx = tid; idx < (8*ARR)/2; idx += 1024) ((u32*)smem)[idx] = 0u;

  // ---- weights (own depth, own 16-feature tile), hi/lo bf16 split
  const float* Wh = (g == 0 ? Whx : Why) + dep*H2n*Hn;
  const int nb = nt*16 + c;
  i32x4 whf_h[4], whf_l[4];
  #pragma unroll
  for (int kk = 0; kk < 4; ++kk){
    #pragma unroll
    for (int p = 0; p < 4; ++p){
      float w0 = Wh[(kk*32 + q*8 + 2*p    )*Hn + nb];
      float w1 = Wh[(kk*32 + q*8 + 2*p + 1)*Hn + nb];
      u32 h0_ = f2bf_rne(w0), h1_ = f2bf_rne(w1);
      u32 l0_ = f2bf_rne(w0 - bf2f((u16)h0_));
      u32 l1_ = f2bf_rne(w1 - bf2f((u16)h1_));
      whf_h[kk][p] = (int)(h0_ | (h1_ << 16));
      whf_l[kk][p] = (int)(l0_ | (l1_ << 16));
    }
  }
  const float* Wi = (g == 0 ? Wix : Wiy) + Hn*Hn;  // depth-1 slice (dep1 only)
  i32x4 wif_h[2], wif_l[2];
  #pragma unroll
  for (int kk = 0; kk < 2; ++kk){
    #pragma unroll
    for (int p = 0; p < 4; ++p){
      float w0 = Wi[(kk*32 + q*8 + 2*p    )*Hn + nb];
      float w1 = Wi[(kk*32 + q*8 + 2*p + 1)*Hn + nb];
      u32 h0_ = f2bf_rne(w0), h1_ = f2bf_rne(w1);
      u32 l0_ = f2bf_rne(w0 - bf2f((u16)h0_));
      u32 l1_ = f2bf_rne(w1 - bf2f((u16)h1_));
      wif_h[kk][p] = (int)(h0_ | (h1_ << 16));
      wif_l[kk][p] = (int)(l0_ | (l1_ << 16));
    }
  }
  f32x4 bias4;  // depth-1 bias (dep0 gets bias via ws projections)
  {
    const float* bb = (g == 0 ? bx : by) + dep*Hn;
    #pragma unroll
    for (int r4 = 0; r4 < 4; ++r4) bias4[r4] = bb[nt*16 + q*4 + r4];
  }
  const float* pxbase = ws + (size_t)(b*2 + g)*Sn*Hn;

  __syncthreads();   // full barrier once: init + weights visible

  for (int r = 0; r < NROUND; ++r){
    const int myd  = r - dep;
    const bool wact = (myd >= 0) && (myd < NDIAG);
    const int i0 = (myd > Tn-1) ? myd - (Tn-1) : 0;
    const int i1 = (myd < Sn-1) ? myd : Sn-1;
    const int nc = i1 - i0 + 1;
    const int mtiles = (nc + 15) >> 4;

    u32x2 hvp[6], lvp[6];   // packed hi/lo results carried across the barrier

    // ---- C phase: read old state, compute; NO state writes
    #pragma unroll
    for (int u = 0; u < 6; ++u){
      const bool act = wact && (u < mtiles);
      if (!act) continue;
      const int cell = u*16 + c;
      const int cc = (cell < nc) ? cell : nc - 1;
      const int i = i0 + cc, j = myd - i;

      f32x4 acc;
      if (dep == 0){
        acc = *(const f32x4*)(pxbase + (size_t)((g == 0) ? i : j)*Hn + nt*16 + q*4);
      } else {
        acc = bias4;
      }
      // recurrence: K=128 (kk0-1: hx from col j; kk2-3: hy from row i)
      #pragma unroll
      for (int kk = 0; kk < 4; ++kk){
        const int off = (kk < 2) ? (j*STR + kk*32 + q*8) : (i*STR + (kk-2)*32 + q*8);
        const u16* hb_ = (kk < 2) ? mXhi : mYhi;
        const u16* lb_ = (kk < 2) ? mXlo : mYlo;
        i32x4 shi = *(const i32x4*)(hb_ + off);
        i32x4 slo = *(const i32x4*)(lb_ + off);
        acc = __builtin_amdgcn_mfma_f32_16x16x32_bf16(
                __builtin_bit_cast(bf16x8, whf_h[kk]),
                __builtin_bit_cast(bf16x8, shi), acc, 0, 0, 0);
        acc = __builtin_amdgcn_mfma_f32_16x16x32_bf16(
                __builtin_bit_cast(bf16x8, whf_h[kk]),
                __builtin_bit_cast(bf16x8, slo), acc, 0, 0, 0);
        acc = __builtin_amdgcn_mfma_f32_16x16x32_bf16(
                __builtin_bit_cast(bf16x8, whf_l[kk]),
                __builtin_bit_cast(bf16x8, shi), acc, 0, 0, 0);
      }
      // depth-1 projection: operand = depth-0 h at (i,j) straight from LDS
      if (dep == 1){
        const int pr = ((g == 0) ? j : i)*STR;
        #pragma unroll
        for (int kk = 0; kk < 2; ++kk){
          i32x4 ph = *(const i32x4*)(pHi + pr + kk*32 + q*8);
          i32x4 pl = *(const i32x4*)(pLo + pr + kk*32 + q*8);
          acc = __builtin_amdgcn_mfma_f32_16x16x32_bf16(
                  __builtin_bit_cast(bf16x8, wif_h[kk]),
                  __builtin_bit_cast(bf16x8, ph), acc, 0, 0, 0);
          acc = __builtin_amdgcn_mfma_f32_16x16x32_bf16(
                  __builtin_bit_cast(bf16x8, wif_h[kk]),
                  __builtin_bit_cast(bf16x8, pl), acc, 0, 0, 0);
          acc = __builtin_amdgcn_mfma_f32_16x16x32_bf16(
                  __builtin_bit_cast(bf16x8, wif_l[kk]),
                  __builtin_bit_cast(bf16x8, ph), acc, 0, 0, 0);  // FIX: W_lo*h_hi (was pl)
        }
      }
      // tanh -> HW packed hi/lo split (RNE both levels)
      float h0 = fast_tanh(acc[0]), h1 = fast_tanh(acc[1]);
      float h2 = fast_tanh(acc[2]), h3 = fast_tanh(acc[3]);
      u32 hv01 = cvt_pk_bf16(h0, h1);
      u32 hv23 = cvt_pk_bf16(h2, h3);
      float l0 = h0 - lo16f(hv01);
      float l1 = h1 - hi16f(hv01);
      float l2 = h2 - lo16f(hv23);
      float l3 = h3 - hi16f(hv23);
      hvp[u][0] = hv01; hvp[u][1] = hv23;
      lvp[u][0] = cvt_pk_bf16(l0, l1);
      lvp[u][1] = cvt_pk_bf16(l2, l3);
    }
    barrier_lds_only();

    // ---- W phase: write state + masked global outputs
    #pragma unroll
    for (int u = 0; u < 6; ++u){
      const bool act = wact && (u < mtiles);
      const int cell = u*16 + c;
      if (!act || cell >= nc) continue;
      const int i = i0 + cell, j = myd - i;
      const int n0 = nt*16 + q*4;
      u16* st_hi = ((g == 0) ? (mXhi + j*STR) : (mYhi + i*STR)) + n0;
      u16* st_lo = ((g == 0) ? (mXlo + j*STR) : (mYlo + i*STR)) + n0;
      *(u32x2*)st_hi = hvp[u];
      *(u32x2*)st_lo = lvp[u];
      const bool mok = (i < sl) && (j < tl);
      f32x4 ov;
      ov[0] = lo16f(hvp[u][0]) + lo16f(lvp[u][0]);
      ov[1] = hi16f(hvp[u][0]) + hi16f(lvp[u][0]);
      ov[2] = lo16f(hvp[u][1]) + lo16f(lvp[u][1]);
      ov[3] = hi16f(hvp[u][1]) + hi16f(lvp[u][1]);
      if (!mok) ov = (f32x4)(0.f);
      float* outg = out + ((size_t)((g*2 + dep)*Bn + b)*(Sn*Tn) + i*Tn + j)*Hn + n0;
      *(f32x4*)outg = ov;
    }
    barrier_lds_only();
  }
}

extern "C" void kernel_launch(void* const* d_in, const int* in_sizes, int n_in,
                              void* d_out, int out_size, void* d_ws, size_t ws_size,
                              hipStream_t stream) {
  (void)in_sizes; (void)n_in; (void)out_size; (void)ws_size;
  (void)hipFuncSetAttribute((const void*)grid_rnn_fused,
                            hipFuncAttributeMaxDynamicSharedMemorySize, 8*ARR*2);
  proj0_kernel<<<dim3(Sn, 2, Bn), 64, 0, stream>>>(
      (const float*)d_in[0], (const float*)d_in[1],
      (const float*)d_in[2], (const float*)d_in[5],
      (const float*)d_in[4], (const float*)d_in[7],
      (float*)d_ws);
  grid_rnn_fused<<<dim3(Bn), dim3(1024), 8*ARR*2, stream>>>(
      (const float*)d_in[3], (const float*)d_in[6],
      (const float*)d_in[2], (const float*)d_in[5],
      (const float*)d_in[4], (const float*)d_in[7],
      (const int*)d_in[8], (const int*)d_in[9],
      (float*)d_out, (const float*)d_ws);
}